// Round 5
// baseline (20373.383 us; speedup 1.0000x reference)
//
#include <hip/hip_runtime.h>
#include <hip/hip_fp16.h>
#include <math.h>

#define TT 833          // output timesteps
#define GDIM 1024       // 4*H gates

__device__ __forceinline__ float sigm(float x){ return 1.f/(1.f+expf(-x)); }

// ---------------- level smoothing scan ----------------
__global__ void levels_k(const float* __restrict__ train, const float* __restrict__ ism,
                         float* __restrict__ levs){
  int b = threadIdx.x;
  if (b >= 32) return;
  float a = 1.f/(1.f+expf(-ism[0]));
  const float* tr = train + b*1024;
  float* lv = levs + b*1024;
  float lev = fmaxf(tr[0], 0.1f);
  lv[0] = lev;
  for (int t = 1; t < 1024; ++t){
    lev = fmaxf(a*tr[t] + (1.f-a)*lev, 0.1f);
    lv[t] = lev;
  }
}

// ---------------- normalized input windows x0[t*32+b][168] ----------------
__global__ void win_x_k(const float* __restrict__ train, const float* __restrict__ levs,
                        float* __restrict__ x0){
  int idx = blockIdx.x*256 + threadIdx.x;   // exactly 833*32*168
  int i = idx % 168;
  int r = idx / 168;       // t*32+b
  int b = r & 31;
  int t = r >> 5;
  x0[idx] = train[b*1024 + t + i] / levs[b*1024 + t + 167];
}

// ---------------- out_win -> d_out second half ----------------
__global__ void win_out_k(const float* __restrict__ train, const float* __restrict__ levs,
                          float* __restrict__ ow){
  int idx = blockIdx.x*256 + threadIdx.x;   // exactly 833*32*24
  int o = idx % 24;
  int r = idx / 24;
  int b = r & 31;
  int t = r >> 5;
  ow[idx] = train[b*1024 + 168 + t + o] / levs[b*1024 + t + 167];
}

// ---------------- pack whh[1024][256] fp32 -> wp[k4][512] uint4 of 8 halves ----------------
// wp[k4][t] = {w[t][4k4..4k4+3], w[t+512][4k4..4k4+3]} as fp16.
__global__ void pack_k(const float* __restrict__ w, uint4* __restrict__ wp){
  int idx = blockIdx.x*256 + threadIdx.x;   // 32768
  int t = idx & 511, k4 = idx >> 9;
  float4 a = *reinterpret_cast<const float4*>(w + (size_t)t*256 + k4*4);
  float4 b = *reinterpret_cast<const float4*>(w + (size_t)(t+512)*256 + k4*4);
  union { uint4 u; __half h[8]; } r;
  r.h[0]=__float2half(a.x); r.h[1]=__float2half(a.y); r.h[2]=__float2half(a.z); r.h[3]=__float2half(a.w);
  r.h[4]=__float2half(b.x); r.h[5]=__float2half(b.y); r.h[6]=__float2half(b.z); r.h[7]=__float2half(b.w);
  wp[(size_t)k4*512 + t] = r.u;
}

// ---------------- generic fp32 GEMM: C[m][n] = A[map(m)][:K] . W[n][:K] + b1 (+b2), opt tanh
__global__ __launch_bounds__(256) void proj_gemm(
    const float* __restrict__ A, const float* __restrict__ W,
    const float* __restrict__ b1, const float* __restrict__ b2,
    float* __restrict__ C, int Mout, int K, int N, int dil, int act)
{
  __shared__ float As[16][68];
  __shared__ float Bs[16][68];
  int tid = threadIdx.x;
  int tx = tid & 15, ty = tid >> 4;
  int m0 = blockIdx.y << 6, n0 = blockIdx.x << 6;
  int amap[4];
  #pragma unroll
  for (int i = 0; i < 4; ++i){
    int m = m0 + (tid >> 4) + i*16;
    int row;
    if (dil == 0){ row = (m < Mout) ? m : -1; }
    else {
      int rows = dil << 5;
      int j = m / rows;
      int q = m - j*rows;
      int t = j*dil + (q >> 5);
      row = (t < TT) ? ((t << 5) + (q & 31)) : -1;
    }
    amap[i] = row;
  }
  float acc[4][4] = {{0.f,0.f,0.f,0.f},{0.f,0.f,0.f,0.f},{0.f,0.f,0.f,0.f},{0.f,0.f,0.f,0.f}};
  int nkt = (K + 15) >> 4;
  for (int kt = 0; kt < nkt; ++kt){
    int kk = (kt << 4) + (tid & 15);
    bool kin = kk < K;
    #pragma unroll
    for (int i = 0; i < 4; ++i){
      int ml = (tid >> 4) + i*16;
      As[tid & 15][ml] = (kin && amap[i] >= 0) ? A[(size_t)amap[i]*K + kk] : 0.f;
      Bs[tid & 15][ml] = kin ? W[(size_t)(n0 + ml)*K + kk] : 0.f;
    }
    __syncthreads();
    #pragma unroll
    for (int k = 0; k < 16; ++k){
      float4 av = *reinterpret_cast<const float4*>(&As[k][ty << 2]);
      float4 bv = *reinterpret_cast<const float4*>(&Bs[k][tx << 2]);
      float a4[4] = {av.x, av.y, av.z, av.w};
      float b4[4] = {bv.x, bv.y, bv.z, bv.w};
      #pragma unroll
      for (int i = 0; i < 4; ++i)
        #pragma unroll
        for (int j = 0; j < 4; ++j)
          acc[i][j] = fmaf(a4[i], b4[j], acc[i][j]);
    }
    __syncthreads();
  }
  #pragma unroll
  for (int i = 0; i < 4; ++i){
    int m = m0 + (ty << 2) + i;
    if (m >= Mout) continue;
    #pragma unroll
    for (int j = 0; j < 4; ++j){
      int n = n0 + (tx << 2) + j;
      float v = acc[i][j] + b1[n] + (b2 ? b2[n] : 0.f);
      if (act) v = tanhf(v);
      C[(size_t)m*N + n] = v;
    }
  }
}

// ---------------- CU-resident-weight dilated-LSTM recurrence ----------------
// One WG owns NR whole rows; zero cross-WG traffic. The 64 weight slabs
// (wp[k4][512] uint4 = 8KB each, 512KB total fp16) are partitioned:
//   k4 in [0,WREG)            -> pinned in VGPRs (WREG*4 regs/thread, static idx)
//   k4 in [WREG,WREG+WLDS)    -> LDS
//   k4 in [WREG+WLDS,64)      -> streamed from L2 each step (only when compute-bound)
// h[256] per row in LDS fp32 (broadcast reads), c in LDS. Thread t owns gate
// rows t and t+512. Gates: i=[0,256) f=[256,512) g=[512,768) o=[768,1024).
template<int NR, int WREG, int WLDS>
__global__ __launch_bounds__(512, 2) void srec_k(
    const uint4* __restrict__ wp, const float* __restrict__ Gin,
    float* __restrict__ out, const float* __restrict__ res,
    int nsteps, int d, int rowsTotal)
{
  constexpr int NSTREAM = 64 - WREG - WLDS;
  extern __shared__ char smc[];
  uint4*  wlds = reinterpret_cast<uint4*>(smc);                       // [WLDS*512]
  float4* hh   = reinterpret_cast<float4*>(smc + WLDS*8192);          // [NR][64]
  float*  psum = reinterpret_cast<float*>(smc + WLDS*8192 + NR*1024); // [NR][1024]
  float*  cst  = reinterpret_cast<float*>(smc + WLDS*8192 + NR*1024 + NR*4096); // [NR][256]
  const int tid = threadIdx.x;
  const int q0 = blockIdx.x*NR;

  // pin WREG slabs in registers (fully static indexing)
  uint4 wreg[WREG];
  #pragma unroll
  for (int k = 0; k < WREG; ++k) wreg[k] = wp[(size_t)k*512 + tid];
  // LDS slabs
  for (int e = tid; e < WLDS*512; e += 512) wlds[e] = wp[(size_t)WREG*512 + e];
  for (int e = tid; e < NR*64; e += 512) hh[e] = make_float4(0.f,0.f,0.f,0.f);
  for (int e = tid; e < NR*256; e += 512) cst[e] = 0.f;
  __syncthreads();

  for (int step = 0; step < nsteps; ++step){
    float ginA[NR], ginB[NR];
    const float* gbase = Gin + ((size_t)step*rowsTotal + q0)*GDIM;
    #pragma unroll
    for (int rr = 0; rr < NR; ++rr){
      ginA[rr] = gbase[rr*GDIM + tid];
      ginB[rr] = gbase[rr*GDIM + tid + 512];
    }
    float accA0[NR], accA1[NR], accB0[NR], accB1[NR];
    #pragma unroll
    for (int rr = 0; rr < NR; ++rr){ accA0[rr]=0.f; accA1[rr]=0.f; accB0[rr]=0.f; accB1[rr]=0.f; }

#define SLAB_BODY(WVAL, K4)                                              \
    {                                                                    \
      union { uint4 u; __half2 h2[4]; } wu_; wu_.u = (WVAL);             \
      float w0 = __half2float(__low2half(wu_.h2[0]));                    \
      float w1 = __half2float(__high2half(wu_.h2[0]));                   \
      float w2 = __half2float(__low2half(wu_.h2[1]));                    \
      float w3 = __half2float(__high2half(wu_.h2[1]));                   \
      float w4 = __half2float(__low2half(wu_.h2[2]));                    \
      float w5 = __half2float(__high2half(wu_.h2[2]));                   \
      float w6 = __half2float(__low2half(wu_.h2[3]));                    \
      float w7 = __half2float(__high2half(wu_.h2[3]));                   \
      _Pragma("unroll")                                                  \
      for (int rr = 0; rr < NR; ++rr){                                   \
        float4 h4 = hh[rr*64 + (K4)];                                    \
        accA0[rr] = fmaf(w0, h4.x, accA0[rr]);                           \
        accA1[rr] = fmaf(w1, h4.y, accA1[rr]);                           \
        accA0[rr] = fmaf(w2, h4.z, accA0[rr]);                           \
        accA1[rr] = fmaf(w3, h4.w, accA1[rr]);                           \
        accB0[rr] = fmaf(w4, h4.x, accB0[rr]);                           \
        accB1[rr] = fmaf(w5, h4.y, accB1[rr]);                           \
        accB0[rr] = fmaf(w6, h4.z, accB0[rr]);                           \
        accB1[rr] = fmaf(w7, h4.w, accB1[rr]);                           \
      }                                                                  \
    }

    #pragma unroll
    for (int k4 = 0; k4 < WREG; ++k4) SLAB_BODY(wreg[k4], k4)
    #pragma unroll
    for (int j = 0; j < WLDS; ++j) SLAB_BODY(wlds[j*512 + tid], WREG + j)
    #pragma unroll
    for (int j = 0; j < NSTREAM; ++j)
      SLAB_BODY(wp[(size_t)(WREG + WLDS + j)*512 + tid], WREG + WLDS + j)
#undef SLAB_BODY

    #pragma unroll
    for (int rr = 0; rr < NR; ++rr){
      psum[rr*1024 + tid]       = accA0[rr] + accA1[rr] + ginA[rr];
      psum[rr*1024 + tid + 512] = accB0[rr] + accB1[rr] + ginB[rr];
    }
    __syncthreads();
    if (tid < 256){
      #pragma unroll
      for (int rr = 0; rr < NR; ++rr){
        float iv = psum[rr*1024 + tid];
        float fv = psum[rr*1024 + tid + 256];
        float gv = psum[rr*1024 + tid + 512];
        float ov = psum[rr*1024 + tid + 768];
        float c = cst[rr*256 + tid];
        c = sigm(fv)*c + sigm(iv)*tanhf(gv);
        float h = sigm(ov)*tanhf(c);
        cst[rr*256 + tid] = c;
        reinterpret_cast<float*>(hh + rr*64)[tid] = h;
        int q = q0 + rr;
        int tg = step*d + (q >> 5);
        if (tg < TT){
          size_t oi = ((size_t)tg*32 + (q & 31))*256 + tid;
          out[oi] = res ? (h + res[oi]) : h;
        }
      }
    }
    __syncthreads();
  }
}

// ---------------- scoring head: pred[m][24] = xt[m][:] . sc_w[n][:] + sc_b ----------------
__global__ __launch_bounds__(256) void sc_head(const float* __restrict__ xt, const float* __restrict__ w,
                        const float* __restrict__ bias, float* __restrict__ outp, int M){
  __shared__ float arow[8][256];
  int m0 = blockIdx.x << 3;
  int tid = threadIdx.x;
  #pragma unroll
  for (int i = 0; i < 8; ++i){
    int e = tid + (i << 8);
    int r = e >> 8, k = e & 255;
    arow[r][k] = (m0 + r < M) ? xt[(size_t)(m0 + r)*256 + k] : 0.f;
  }
  __syncthreads();
  int r = tid >> 5, n = tid & 31;
  if (n < 24 && (m0 + r) < M){
    float acc = bias[n];
    const float* wr = w + n*256;
    #pragma unroll 8
    for (int k = 0; k < 256; ++k) acc = fmaf(arow[r][k], wr[k], acc);
    outp[(size_t)(m0 + r)*24 + n] = acc;
  }
}

extern "C" void kernel_launch(void* const* d_in, const int* in_sizes, int n_in,
                              void* d_out, int out_size, void* d_ws, size_t ws_size,
                              hipStream_t stream){
  const float* train = (const float*)d_in[0];
  const float* ism   = (const float*)d_in[4];
  const float* wih[4] = {(const float*)d_in[5], (const float*)d_in[9], (const float*)d_in[13], (const float*)d_in[17]};
  const float* whh[4] = {(const float*)d_in[6], (const float*)d_in[10], (const float*)d_in[14], (const float*)d_in[18]};
  const float* bih[4] = {(const float*)d_in[7], (const float*)d_in[11], (const float*)d_in[15], (const float*)d_in[19]};
  const float* bhh[4] = {(const float*)d_in[8], (const float*)d_in[12], (const float*)d_in[16], (const float*)d_in[20]};
  const float* nl_w = (const float*)d_in[21];
  const float* nl_b = (const float*)d_in[22];
  const float* sc_w = (const float*)d_in[23];
  const float* sc_b = (const float*)d_in[24];
  float* out = (float*)d_out;

  float* ws = (float*)d_ws;
  size_t off = 0;
  float* levs = ws + off;   off += 32768;
  uint4* wpk[4];
  for (int l = 0; l < 4; ++l){ wpk[l] = (uint4*)(ws + off); off += 131072; }  // 512KB each
  float* x0 = ws + off;     off += (size_t)26656*168;
  float* G  = ws + off;     off += (size_t)28672*1024;
  float* h0 = ws + off;     off += (size_t)26656*256;
  float* h1 = ws + off;     off += (size_t)26656*256;
  float* h2 = ws + off;     off += (size_t)26656*256;
  (void)ws_size; (void)in_sizes; (void)n_in; (void)out_size;

  levels_k<<<1, 64, 0, stream>>>(train, ism, levs);
  win_x_k<<<17493, 256, 0, stream>>>(train, levs, x0);
  win_out_k<<<2499, 256, 0, stream>>>(train, levs, out + 639744);
  for (int l = 0; l < 4; ++l)
    pack_k<<<128, 256, 0, stream>>>(whh[l], wpk[l]);

  // dynamic-LDS sizes: WLDS*8192 + NR*6144
  const int SM1 = 18*8192 + 1*6144;    // 153600
  const int SM2 = 18*8192 + 2*6144;    // 159744
  const int SM8 = 13*8192 + 8*6144;    // 155648
  hipFuncSetAttribute(reinterpret_cast<const void*>(&srec_k<1,46,18>),
                      hipFuncAttributeMaxDynamicSharedMemorySize, SM1);
  hipFuncSetAttribute(reinterpret_cast<const void*>(&srec_k<2,46,18>),
                      hipFuncAttributeMaxDynamicSharedMemorySize, SM2);
  hipFuncSetAttribute(reinterpret_cast<const void*>(&srec_k<8,32,13>),
                      hipFuncAttributeMaxDynamicSharedMemorySize, SM8);

  // layer 0 (d=1): 833 steps, 32 rows -> 32 WGs x 1 row
  proj_gemm<<<dim3(16,417), 256, 0, stream>>>(x0, wih[0], bih[0], bhh[0], G, 26656, 168, 1024, 0, 0);
  srec_k<1,46,18><<<32, 512, SM1, stream>>>(wpk[0], G, h0, nullptr, 833, 1, 32);
  // layer 1 (d=4): 209 steps, 128 rows -> 128 WGs x 1 row
  proj_gemm<<<dim3(16,418), 256, 0, stream>>>(h0, wih[1], bih[1], bhh[1], G, 26752, 256, 1024, 4, 0);
  srec_k<1,46,18><<<128, 512, SM1, stream>>>(wpk[1], G, h1, nullptr, 209, 4, 128);
  // layer 2 (d=16): 53 steps, 512 rows -> 256 WGs x 2 rows
  proj_gemm<<<dim3(16,424), 256, 0, stream>>>(h1, wih[2], bih[2], bhh[2], G, 27136, 256, 1024, 16, 0);
  srec_k<2,46,18><<<256, 512, SM2, stream>>>(wpk[2], G, h2, nullptr, 53, 16, 512);
  // layer 3 (d=64): 14 steps, 2048 rows -> 256 WGs x 8 rows; residual h1; out overwrites h2
  proj_gemm<<<dim3(16,448), 256, 0, stream>>>(h2, wih[3], bih[3], bhh[3], G, 28672, 256, 1024, 64, 0);
  srec_k<8,32,13><<<256, 512, SM8, stream>>>(wpk[3], G, h2, h1, 14, 64, 2048);
  // nonlinear dense: xt = tanh(xf @ nl_w.T + nl_b)  (reuse h0)
  proj_gemm<<<dim3(4,417), 256, 0, stream>>>(h2, nl_w, nl_b, nullptr, h0, 26656, 256, 256, 0, 1);
  // scoring head -> pred (first half of d_out)
  sc_head<<<3332, 256, 0, stream>>>(h0, sc_w, sc_b, out, 26656);
}

// Round 6
// 18393.854 us; speedup vs baseline: 1.1076x; 1.1076x over previous
//
#include <hip/hip_runtime.h>
#include <hip/hip_fp16.h>
#include <math.h>

#define TT 833          // output timesteps
#define GDIM 1024       // 4*H gates

__device__ __forceinline__ float sigm(float x){ return 1.f/(1.f+expf(-x)); }

// ---------------- level smoothing scan ----------------
__global__ void levels_k(const float* __restrict__ train, const float* __restrict__ ism,
                         float* __restrict__ levs){
  int b = threadIdx.x;
  if (b >= 32) return;
  float a = 1.f/(1.f+expf(-ism[0]));
  const float* tr = train + b*1024;
  float* lv = levs + b*1024;
  float lev = fmaxf(tr[0], 0.1f);
  lv[0] = lev;
  for (int t = 1; t < 1024; ++t){
    lev = fmaxf(a*tr[t] + (1.f-a)*lev, 0.1f);
    lv[t] = lev;
  }
}

// ---------------- normalized input windows x0[t*32+b][168] ----------------
__global__ void win_x_k(const float* __restrict__ train, const float* __restrict__ levs,
                        float* __restrict__ x0){
  int idx = blockIdx.x*256 + threadIdx.x;   // exactly 833*32*168
  int i = idx % 168;
  int r = idx / 168;       // t*32+b
  int b = r & 31;
  int t = r >> 5;
  x0[idx] = train[b*1024 + t + i] / levs[b*1024 + t + 167];
}

// ---------------- out_win -> d_out second half ----------------
__global__ void win_out_k(const float* __restrict__ train, const float* __restrict__ levs,
                          float* __restrict__ ow){
  int idx = blockIdx.x*256 + threadIdx.x;   // exactly 833*32*24
  int o = idx % 24;
  int r = idx / 24;
  int b = r & 31;
  int t = r >> 5;
  ow[idx] = train[b*1024 + 168 + t + o] / levs[b*1024 + t + 167];
}

// ---------------- pack whh[1024][256] fp32 -> wp[k4][512] uint4 of 8 halves ----------------
// wp[k4][t] = {w[t][4k4..4k4+3], w[t+512][4k4..4k4+3]} as fp16.
__global__ void pack_k(const float* __restrict__ w, uint4* __restrict__ wp){
  int idx = blockIdx.x*256 + threadIdx.x;   // 32768
  int t = idx & 511, k4 = idx >> 9;
  float4 a = *reinterpret_cast<const float4*>(w + (size_t)t*256 + k4*4);
  float4 b = *reinterpret_cast<const float4*>(w + (size_t)(t+512)*256 + k4*4);
  union { uint4 u; __half h[8]; } r;
  r.h[0]=__float2half(a.x); r.h[1]=__float2half(a.y); r.h[2]=__float2half(a.z); r.h[3]=__float2half(a.w);
  r.h[4]=__float2half(b.x); r.h[5]=__float2half(b.y); r.h[6]=__float2half(b.z); r.h[7]=__float2half(b.w);
  wp[(size_t)k4*512 + t] = r.u;
}

// ---------------- generic fp32 GEMM: C[m][n] = A[map(m)][:K] . W[n][:K] + b1 (+b2), opt tanh
__global__ __launch_bounds__(256) void proj_gemm(
    const float* __restrict__ A, const float* __restrict__ W,
    const float* __restrict__ b1, const float* __restrict__ b2,
    float* __restrict__ C, int Mout, int K, int N, int dil, int act)
{
  __shared__ float As[16][68];
  __shared__ float Bs[16][68];
  int tid = threadIdx.x;
  int tx = tid & 15, ty = tid >> 4;
  int m0 = blockIdx.y << 6, n0 = blockIdx.x << 6;
  int amap[4];
  #pragma unroll
  for (int i = 0; i < 4; ++i){
    int m = m0 + (tid >> 4) + i*16;
    int row;
    if (dil == 0){ row = (m < Mout) ? m : -1; }
    else {
      int rows = dil << 5;
      int j = m / rows;
      int q = m - j*rows;
      int t = j*dil + (q >> 5);
      row = (t < TT) ? ((t << 5) + (q & 31)) : -1;
    }
    amap[i] = row;
  }
  float acc[4][4] = {{0.f,0.f,0.f,0.f},{0.f,0.f,0.f,0.f},{0.f,0.f,0.f,0.f},{0.f,0.f,0.f,0.f}};
  int nkt = (K + 15) >> 4;
  for (int kt = 0; kt < nkt; ++kt){
    int kk = (kt << 4) + (tid & 15);
    bool kin = kk < K;
    #pragma unroll
    for (int i = 0; i < 4; ++i){
      int ml = (tid >> 4) + i*16;
      As[tid & 15][ml] = (kin && amap[i] >= 0) ? A[(size_t)amap[i]*K + kk] : 0.f;
      Bs[tid & 15][ml] = kin ? W[(size_t)(n0 + ml)*K + kk] : 0.f;
    }
    __syncthreads();
    #pragma unroll
    for (int k = 0; k < 16; ++k){
      float4 av = *reinterpret_cast<const float4*>(&As[k][ty << 2]);
      float4 bv = *reinterpret_cast<const float4*>(&Bs[k][tx << 2]);
      float a4[4] = {av.x, av.y, av.z, av.w};
      float b4[4] = {bv.x, bv.y, bv.z, bv.w};
      #pragma unroll
      for (int i = 0; i < 4; ++i)
        #pragma unroll
        for (int j = 0; j < 4; ++j)
          acc[i][j] = fmaf(a4[i], b4[j], acc[i][j]);
    }
    __syncthreads();
  }
  #pragma unroll
  for (int i = 0; i < 4; ++i){
    int m = m0 + (ty << 2) + i;
    if (m >= Mout) continue;
    #pragma unroll
    for (int j = 0; j < 4; ++j){
      int n = n0 + (tx << 2) + j;
      float v = acc[i][j] + b1[n] + (b2 ? b2[n] : 0.f);
      if (act) v = tanhf(v);
      C[(size_t)m*N + n] = v;
    }
  }
}

// ---------------- CU-resident-weight dilated-LSTM recurrence ----------------
// One WG owns NR whole rows; zero cross-WG traffic. 64 weight slabs (8KB each):
//   [0,WREG)           -> VGPR-pinned (WREG*4 regs/thread; keep WREG small —
//                         round-5 lesson: a 184-reg array under a 128-reg cap
//                         spills the lot to scratch, 965MB/dispatch HBM traffic)
//   [WREG,WREG+WLDS)   -> LDS
//   rest               -> streamed from L2 each step
// h[256]/row + c in LDS fp32. Thread t owns gate rows t, t+512.
template<int NR, int WREG, int WLDS>
__global__ __launch_bounds__(512, 1) void srec_k(
    const uint4* __restrict__ wp, const float* __restrict__ Gin,
    float* __restrict__ out, const float* __restrict__ res,
    int nsteps, int d, int rowsTotal)
{
  constexpr int NSTREAM = 64 - WREG - WLDS;
  extern __shared__ char smc[];
  uint4*  wlds = reinterpret_cast<uint4*>(smc);                       // [WLDS*512]
  float4* hh   = reinterpret_cast<float4*>(smc + WLDS*8192);          // [NR][64]
  float*  psum = reinterpret_cast<float*>(smc + WLDS*8192 + NR*1024); // [NR][1024]
  float*  cst  = reinterpret_cast<float*>(smc + WLDS*8192 + NR*1024 + NR*4096); // [NR][256]
  const int tid = threadIdx.x;
  const int q0 = blockIdx.x*NR;

  uint4 wreg[WREG];
  #pragma unroll
  for (int k = 0; k < WREG; ++k) wreg[k] = wp[(size_t)k*512 + tid];
  for (int e = tid; e < WLDS*512; e += 512) wlds[e] = wp[(size_t)WREG*512 + e];
  for (int e = tid; e < NR*64; e += 512) hh[e] = make_float4(0.f,0.f,0.f,0.f);
  for (int e = tid; e < NR*256; e += 512) cst[e] = 0.f;
  __syncthreads();

  for (int step = 0; step < nsteps; ++step){
    float ginA[NR], ginB[NR];
    const float* gbase = Gin + ((size_t)step*rowsTotal + q0)*GDIM;
    #pragma unroll
    for (int rr = 0; rr < NR; ++rr){
      ginA[rr] = gbase[rr*GDIM + tid];
      ginB[rr] = gbase[rr*GDIM + tid + 512];
    }
    float accA0[NR], accA1[NR], accB0[NR], accB1[NR];
    #pragma unroll
    for (int rr = 0; rr < NR; ++rr){ accA0[rr]=0.f; accA1[rr]=0.f; accB0[rr]=0.f; accB1[rr]=0.f; }

#define SLAB_BODY(WVAL, K4)                                              \
    {                                                                    \
      union { uint4 u; __half2 h2[4]; } wu_; wu_.u = (WVAL);             \
      float w0 = __half2float(__low2half(wu_.h2[0]));                    \
      float w1 = __half2float(__high2half(wu_.h2[0]));                   \
      float w2 = __half2float(__low2half(wu_.h2[1]));                    \
      float w3 = __half2float(__high2half(wu_.h2[1]));                   \
      float w4 = __half2float(__low2half(wu_.h2[2]));                    \
      float w5 = __half2float(__high2half(wu_.h2[2]));                   \
      float w6 = __half2float(__low2half(wu_.h2[3]));                    \
      float w7 = __half2float(__high2half(wu_.h2[3]));                   \
      _Pragma("unroll")                                                  \
      for (int rr = 0; rr < NR; ++rr){                                   \
        float4 h4 = hh[rr*64 + (K4)];                                    \
        accA0[rr] = fmaf(w0, h4.x, accA0[rr]);                           \
        accA1[rr] = fmaf(w1, h4.y, accA1[rr]);                           \
        accA0[rr] = fmaf(w2, h4.z, accA0[rr]);                           \
        accA1[rr] = fmaf(w3, h4.w, accA1[rr]);                           \
        accB0[rr] = fmaf(w4, h4.x, accB0[rr]);                           \
        accB1[rr] = fmaf(w5, h4.y, accB1[rr]);                           \
        accB0[rr] = fmaf(w6, h4.z, accB0[rr]);                           \
        accB1[rr] = fmaf(w7, h4.w, accB1[rr]);                           \
      }                                                                  \
    }

    #pragma unroll
    for (int k4 = 0; k4 < WREG; ++k4) SLAB_BODY(wreg[k4], k4)
    #pragma unroll
    for (int j = 0; j < WLDS; ++j) SLAB_BODY(wlds[j*512 + tid], WREG + j)
    #pragma unroll
    for (int j = 0; j < NSTREAM; ++j)
      SLAB_BODY(wp[(size_t)(WREG + WLDS + j)*512 + tid], WREG + WLDS + j)
#undef SLAB_BODY

    #pragma unroll
    for (int rr = 0; rr < NR; ++rr){
      psum[rr*1024 + tid]       = accA0[rr] + accA1[rr] + ginA[rr];
      psum[rr*1024 + tid + 512] = accB0[rr] + accB1[rr] + ginB[rr];
    }
    __syncthreads();
    if (tid < 256){
      #pragma unroll
      for (int rr = 0; rr < NR; ++rr){
        float iv = psum[rr*1024 + tid];
        float fv = psum[rr*1024 + tid + 256];
        float gv = psum[rr*1024 + tid + 512];
        float ov = psum[rr*1024 + tid + 768];
        float c = cst[rr*256 + tid];
        c = sigm(fv)*c + sigm(iv)*tanhf(gv);
        float h = sigm(ov)*tanhf(c);
        cst[rr*256 + tid] = c;
        reinterpret_cast<float*>(hh + rr*64)[tid] = h;
        int q = q0 + rr;
        int tg = step*d + (q >> 5);
        if (tg < TT){
          size_t oi = ((size_t)tg*32 + (q & 31))*256 + tid;
          out[oi] = res ? (h + res[oi]) : h;
        }
      }
    }
    __syncthreads();
  }
}

// ---------------- scoring head: pred[m][24] = xt[m][:] . sc_w[n][:] + sc_b ----------------
__global__ __launch_bounds__(256) void sc_head(const float* __restrict__ xt, const float* __restrict__ w,
                        const float* __restrict__ bias, float* __restrict__ outp, int M){
  __shared__ float arow[8][256];
  int m0 = blockIdx.x << 3;
  int tid = threadIdx.x;
  #pragma unroll
  for (int i = 0; i < 8; ++i){
    int e = tid + (i << 8);
    int r = e >> 8, k = e & 255;
    arow[r][k] = (m0 + r < M) ? xt[(size_t)(m0 + r)*256 + k] : 0.f;
  }
  __syncthreads();
  int r = tid >> 5, n = tid & 31;
  if (n < 24 && (m0 + r) < M){
    float acc = bias[n];
    const float* wr = w + n*256;
    #pragma unroll 8
    for (int k = 0; k < 256; ++k) acc = fmaf(arow[r][k], wr[k], acc);
    outp[(size_t)(m0 + r)*24 + n] = acc;
  }
}

extern "C" void kernel_launch(void* const* d_in, const int* in_sizes, int n_in,
                              void* d_out, int out_size, void* d_ws, size_t ws_size,
                              hipStream_t stream){
  const float* train = (const float*)d_in[0];
  const float* ism   = (const float*)d_in[4];
  const float* wih[4] = {(const float*)d_in[5], (const float*)d_in[9], (const float*)d_in[13], (const float*)d_in[17]};
  const float* whh[4] = {(const float*)d_in[6], (const float*)d_in[10], (const float*)d_in[14], (const float*)d_in[18]};
  const float* bih[4] = {(const float*)d_in[7], (const float*)d_in[11], (const float*)d_in[15], (const float*)d_in[19]};
  const float* bhh[4] = {(const float*)d_in[8], (const float*)d_in[12], (const float*)d_in[16], (const float*)d_in[20]};
  const float* nl_w = (const float*)d_in[21];
  const float* nl_b = (const float*)d_in[22];
  const float* sc_w = (const float*)d_in[23];
  const float* sc_b = (const float*)d_in[24];
  float* out = (float*)d_out;

  float* ws = (float*)d_ws;
  size_t off = 0;
  float* levs = ws + off;   off += 32768;
  uint4* wpk[4];
  for (int l = 0; l < 4; ++l){ wpk[l] = (uint4*)(ws + off); off += 131072; }  // 512KB each
  float* x0 = ws + off;     off += (size_t)26656*168;
  float* G  = ws + off;     off += (size_t)28672*1024;
  float* h0 = ws + off;     off += (size_t)26656*256;
  float* h1 = ws + off;     off += (size_t)26656*256;
  float* h2 = ws + off;     off += (size_t)26656*256;
  (void)ws_size; (void)in_sizes; (void)n_in; (void)out_size;

  levels_k<<<1, 64, 0, stream>>>(train, ism, levs);
  win_x_k<<<17493, 256, 0, stream>>>(train, levs, x0);
  win_out_k<<<2499, 256, 0, stream>>>(train, levs, out + 639744);
  for (int l = 0; l < 4; ++l)
    pack_k<<<128, 256, 0, stream>>>(whh[l], wpk[l]);

  // dynamic-LDS sizes: WLDS*8192 + NR*6144 (<= 163840)
  const int SM1 = 19*8192 + 1*6144;    // 161792
  const int SM2 = 18*8192 + 2*6144;    // 159744
  const int SM8 = 13*8192 + 8*6144;    // 155648
  hipFuncSetAttribute(reinterpret_cast<const void*>(&srec_k<1,24,19>),
                      hipFuncAttributeMaxDynamicSharedMemorySize, SM1);
  hipFuncSetAttribute(reinterpret_cast<const void*>(&srec_k<2,24,18>),
                      hipFuncAttributeMaxDynamicSharedMemorySize, SM2);
  hipFuncSetAttribute(reinterpret_cast<const void*>(&srec_k<8,24,13>),
                      hipFuncAttributeMaxDynamicSharedMemorySize, SM8);

  // layer 0 (d=1): 833 steps, 32 rows -> 32 WGs x 1 row
  proj_gemm<<<dim3(16,417), 256, 0, stream>>>(x0, wih[0], bih[0], bhh[0], G, 26656, 168, 1024, 0, 0);
  srec_k<1,24,19><<<32, 512, SM1, stream>>>(wpk[0], G, h0, nullptr, 833, 1, 32);
  // layer 1 (d=4): 209 steps, 128 rows -> 128 WGs x 1 row
  proj_gemm<<<dim3(16,418), 256, 0, stream>>>(h0, wih[1], bih[1], bhh[1], G, 26752, 256, 1024, 4, 0);
  srec_k<1,24,19><<<128, 512, SM1, stream>>>(wpk[1], G, h1, nullptr, 209, 4, 128);
  // layer 2 (d=16): 53 steps, 512 rows -> 256 WGs x 2 rows
  proj_gemm<<<dim3(16,424), 256, 0, stream>>>(h1, wih[2], bih[2], bhh[2], G, 27136, 256, 1024, 16, 0);
  srec_k<2,24,18><<<256, 512, SM2, stream>>>(wpk[2], G, h2, nullptr, 53, 16, 512);
  // layer 3 (d=64): 14 steps, 2048 rows -> 256 WGs x 8 rows; residual h1; out overwrites h2
  proj_gemm<<<dim3(16,448), 256, 0, stream>>>(h2, wih[3], bih[3], bhh[3], G, 28672, 256, 1024, 64, 0);
  srec_k<8,24,13><<<256, 512, SM8, stream>>>(wpk[3], G, h2, h1, 14, 64, 2048);
  // nonlinear dense: xt = tanh(xf @ nl_w.T + nl_b)  (reuse h0)
  proj_gemm<<<dim3(4,417), 256, 0, stream>>>(h2, nl_w, nl_b, nullptr, h0, 26656, 256, 256, 0, 1);
  // scoring head -> pred (first half of d_out)
  sc_head<<<3332, 256, 0, stream>>>(h0, sc_w, sc_b, out, 26656);
}